// Round 1
// baseline (154.025 us; speedup 1.0000x reference)
//
#include <hip/hip_runtime.h>
#include <math.h>

#define Bn 128
#define Nn 128
#define Ln 64
#define Pn 30

// workspace layout (float offsets)
// table: [P][N][N] float2  -> 30*16384*2 = 983040 floats
#define ZOFF  983040          // z[P][L]      : 1920 floats
#define VOFF  984960          // valid[P][N]  : 3840 floats
#define ROFF  988800          // rec[B][P]    : 3840 floats
#define KOFF  992640          // KL mean      : 1 float

// ---------------- K1: z (for p<P) + KL mean ----------------
__global__ void k_zkl(const float* __restrict__ mu,
                      const float* __restrict__ logstd,
                      const float* __restrict__ eps,
                      float* __restrict__ ws) {
    int t = threadIdx.x;
    float kl = 0.f;
    for (int idx = t; idx < Bn * Ln; idx += 256) {
        float m  = mu[idx];
        float ls = logstd[idx];
        float e  = eps[idx];
        float z  = m + e * __expf(ls);
        // log_q - log_p per element; 0.5*log(2pi) cancels
        kl += -0.5f * e * e - ls + 0.5f * z * z;
        if (idx < Pn * Ln) ws[ZOFF + idx] = z;   // idx = b*L + l, b < P
    }
    __shared__ float red[256];
    red[t] = kl;
    __syncthreads();
    for (int s = 128; s > 0; s >>= 1) {
        if (t < s) red[t] += red[t + s];
        __syncthreads();
    }
    if (t == 0) ws[KOFF] = red[0] / (float)Bn;
}

// ---------------- K2: logits GEMM + (logsig, l) table + valid ----------------
#define PG 10   // graphs per block group (30/PG = 3 groups)
__global__ void k_table(const float* __restrict__ W,
                        const int* __restrict__ node_masks,
                        float* __restrict__ ws) {
    // grid = 64 uv-chunks * 3 p-groups
    int chunk = blockIdx.x & 63;
    int pg    = blockIdx.x >> 6;
    int t     = threadIdx.x;

    __shared__ float zs[PG][Ln];
    for (int i = t; i < PG * Ln; i += 256)
        zs[i / Ln][i % Ln] = ws[ZOFF + pg * PG * Ln + i];
    __syncthreads();

    int uv = chunk * 256 + t;
    float acc[PG];
#pragma unroll
    for (int q = 0; q < PG; q++) acc[q] = 0.f;

    for (int k = 0; k < Ln; k++) {
        float w = W[k * (Nn * Nn) + uv];
#pragma unroll
        for (int q = 0; q < PG; q++) acc[q] = fmaf(zs[q][k], w, acc[q]);
    }

    float2* tab = (float2*)ws;
#pragma unroll
    for (int q = 0; q < PG; q++) {
        int p = pg * PG + q;
        float l = acc[q];
        // stable log_sigmoid(l)
        float lsg = (l < 0.f) ? (l - log1pf(__expf(l))) : (-log1pf(__expf(-l)));
        tab[p * (Nn * Nn) + uv] = make_float2(lsg, l);
    }

    // extract valid[p][i] = node_masks[p][i][i] once per p-group
    if (chunk == 0) {
        for (int i = t; i < PG * Nn; i += 256) {
            int q = i / Nn, node = i % Nn;
            int p = pg * PG + q;
            ws[VOFF + p * Nn + node] =
                (float)node_masks[p * Nn * Nn + node * Nn + node];
        }
    }
}

// ---------------- K3: hot loop — rec[b][p] ----------------
__global__ __launch_bounds__(256) void k_main(const int* __restrict__ Adj,
                                              const int* __restrict__ perms,
                                              const float* __restrict__ ws,
                                              float* __restrict__ rec) {
    // blockIdx = p*B + b  (consecutive blocks share per-p table slice in L2)
    int p = blockIdx.x >> 7;
    int b = blockIdx.x & (Bn - 1);
    int t = threadIdx.x;

    __shared__ int   perm_s[Nn];
    __shared__ float valid_s[Nn];
    if (t < Nn) {
        perm_s[t]  = perms[(b * Pn + p) * Nn + t];
        valid_s[t] = ws[VOFF + p * Nn + t];
    }
    __syncthreads();

    const float2* tab = ((const float2*)ws) + p * (Nn * Nn);
    const int*    Ap  = Adj + p * (Nn * Nn);

    int   j  = t & (Nn - 1);
    int   i0 = t >> 7;            // i is wave-uniform: waves 0,1 -> 0; waves 2,3 -> 1
    int   pj = perm_s[j];
    float vj = valid_s[j];

    float acc = 0.f;
#pragma unroll 4
    for (int it = 0; it < Nn / 2; ++it) {
        int   i  = it * 2 + i0;
        float vi = valid_s[i];
        if (vi != 0.f) {          // wave-uniform skip of invalid rows
            int    pi = perm_s[i];
            float2 c  = tab[pi * Nn + pj];   // gather within 1KB row (L1/L2)
            int    a  = Ap[i * Nn + j];      // coalesced
            // A=1: logsig(l) ; A=0: logsig(-l) = logsig(l) - l
            float logp = a ? c.x : (c.x - c.y);
            acc += vj * logp;
        }
    }

    __shared__ float red[256];
    red[t] = acc;
    __syncthreads();
    for (int s = 128; s > 0; s >>= 1) {
        if (t < s) red[t] += red[t + s];
        __syncthreads();
    }
    if (t == 0) rec[b * Pn + p] = red[0];
}

// ---------------- K4: RE = sum_b max_p rec ; out = KLmean - RE ----------------
__global__ void k_final(const float* __restrict__ ws, float* __restrict__ out) {
    int t = threadIdx.x;   // 128 threads, one per b
    float m = -INFINITY;
    for (int p = 0; p < Pn; p++) m = fmaxf(m, ws[ROFF + t * Pn + p]);
    __shared__ float red[128];
    red[t] = m;
    __syncthreads();
    for (int s = 64; s > 0; s >>= 1) {
        if (t < s) red[t] += red[t + s];
        __syncthreads();
    }
    if (t == 0) out[0] = ws[KOFF] - red[0];
}

extern "C" void kernel_launch(void* const* d_in, const int* in_sizes, int n_in,
                              void* d_out, int out_size, void* d_ws, size_t ws_size,
                              hipStream_t stream) {
    const float* mu     = (const float*)d_in[0];
    const float* logstd = (const float*)d_in[1];
    const float* eps    = (const float*)d_in[2];
    const float* W      = (const float*)d_in[3];
    const int*   Adj    = (const int*)d_in[4];
    const int*   nm     = (const int*)d_in[5];
    const int*   perms  = (const int*)d_in[6];
    float* ws  = (float*)d_ws;
    float* out = (float*)d_out;

    hipLaunchKernelGGL(k_zkl,   dim3(1),        dim3(256), 0, stream, mu, logstd, eps, ws);
    hipLaunchKernelGGL(k_table, dim3(192),      dim3(256), 0, stream, W, nm, ws);
    hipLaunchKernelGGL(k_main,  dim3(Pn * Bn),  dim3(256), 0, stream, Adj, perms, ws, ws + ROFF);
    hipLaunchKernelGGL(k_final, dim3(1),        dim3(128), 0, stream, ws, out);
}

// Round 2
// 131.489 us; speedup vs baseline: 1.1714x; 1.1714x over previous
//
#include <hip/hip_runtime.h>
#include <hip/hip_fp16.h>
#include <math.h>

#define Bn 128
#define Nn 128
#define Ln 64
#define Pn 30
#define PG 10

// ws layout in 4-byte words:
#define TOFF  0        // tab:    [P][N*N] uint32 = half2{logsig(-l), l} : 491520 words
#define BOFF  491520   // Bpack:  [P][N][4] uint32 bitrows of (mask&Adj): 15360 words
#define VOFFW 506880   // validf: [P][N] float                          : 3840 words
#define ROFF  510720   // rec:    [B][P] float                          : 3840 words

// ---------------- K1: fused table build (logits GEMM + logsig) + bit-pack ----------------
__global__ __launch_bounds__(256) void k_prep(const float* __restrict__ mu,
                                              const float* __restrict__ logstd,
                                              const float* __restrict__ eps,
                                              const float* __restrict__ W,
                                              const int* __restrict__ Adj,
                                              const int* __restrict__ nm,
                                              float* __restrict__ ws) {
    int blk = blockIdx.x, t = threadIdx.x;
    if (blk < 192) {
        // table blocks: 64 uv-chunks x 3 p-groups of PG=10 graphs
        int chunk = blk & 63, pg = blk >> 6;
        __shared__ float zs[PG][Ln];
        for (int idx = t; idx < PG * Ln; idx += 256) {
            int g = pg * PG * Ln + idx;      // graph index == batch index for b < P
            zs[idx / Ln][idx % Ln] = mu[g] + eps[g] * __expf(logstd[g]);
        }
        __syncthreads();
        int uv = chunk * 256 + t;
        float acc[PG];
#pragma unroll
        for (int q = 0; q < PG; q++) acc[q] = 0.f;
        for (int k = 0; k < Ln; k++) {
            float w = W[k * (Nn * Nn) + uv];
#pragma unroll
            for (int q = 0; q < PG; q++) acc[q] = fmaf(zs[q][k], w, acc[q]);
        }
        uint32_t* tab = (uint32_t*)ws;
#pragma unroll
        for (int q = 0; q < PG; q++) {
            int p = pg * PG + q;
            float l = acc[q];
            float nl = -l;
            // logsig(-l), numerically stable
            float lsneg = (nl < 0.f) ? (nl - log1pf(__expf(nl))) : (-log1pf(__expf(-nl)));
            __half2 h = __floats2half2_rn(lsneg, l);
            tab[p * (Nn * Nn) + uv] = *(uint32_t*)&h;
        }
    } else {
        // bit-pack blocks: one per graph p. B = node_mask & Adj, 128 rows x 128 bits
        int p = blk - 192;
        __shared__ float val_s[Nn];
        if (t < Nn) {
            float v = (float)nm[p * Nn * Nn + t * Nn + t];  // diag = valid[t]
            val_s[t] = v;
            ws[VOFFW + p * Nn + t] = v;
        }
        __syncthreads();
        int sub = t >> 6, lane = t & 63;
        int ioff = sub >> 1, ch = sub & 1;       // 4 waves: 2 rows x 2 column-halves
        int j = ch * 64 + lane;
        uint32_t* Bp = (uint32_t*)ws + BOFF + p * Nn * 4;
        for (int ib = 0; ib < Nn; ib += 2) {
            int i = ib + ioff;
            bool pred = (Adj[p * Nn * Nn + i * Nn + j] != 0) &&
                        (val_s[i] != 0.f) && (val_s[j] != 0.f);
            unsigned long long m = __ballot(pred);
            if (lane == 0) {
                Bp[i * 4 + ch * 2]     = (uint32_t)m;
                Bp[i * 4 + ch * 2 + 1] = (uint32_t)(m >> 32);
            }
        }
    }
}

// ---------------- K2: hot loop — rec[b][p], fully coalesced table stream ----------------
__global__ __launch_bounds__(256) void k_main(const int* __restrict__ perms,
                                              const float* __restrict__ ws,
                                              float* __restrict__ rec) {
    int p = blockIdx.x >> 7;          // consecutive blocks share per-p data in L2
    int b = blockIdx.x & (Bn - 1);
    int t = threadIdx.x;

    __shared__ int      inv_s[Nn];
    __shared__ uint32_t B_s[Nn * 4];
    __shared__ float    red[256];

    if (t < Nn) {
        int pm = perms[(b * Pn + p) * Nn + t];
        inv_s[pm] = t;                // inv[perm[i]] = i
    }
    {
        const uint32_t* Bp = (const uint32_t*)ws + BOFF + p * Nn * 4;
        B_s[t]       = Bp[t];
        B_s[256 + t] = Bp[256 + t];
    }
    __syncthreads();

    const float* validp = ws + VOFFW + p * Nn;
    int   v  = t & (Nn - 1);
    int   i0 = t >> 7;                // wave-parity of the row
    int   j  = inv_s[v];              // loop-invariant per lane
    float wv = validp[j];
    int   wsel = j >> 5, jsh = j & 31;

    // row meta held in lane registers for readlane broadcast: lane k -> row u=2k+i0
    int   lanei   = t & 63;
    int   iu      = inv_s[2 * lanei + i0];
    int   wu_bits = __float_as_int(validp[iu]);

    const uint32_t* tabp = (const uint32_t*)ws + p * (Nn * Nn);
    float acc1 = 0.f, acc2 = 0.f;

#pragma unroll 4
    for (int it = 0; it < 64; ++it) {
        int      si   = __builtin_amdgcn_readlane(iu, it);        // row i (scalar)
        float    swu  = __int_as_float(__builtin_amdgcn_readlane(wu_bits, it));
        uint32_t bits = B_s[si * 4 + wsel];                       // 4 addrs, broadcast
        uint32_t hw   = tabp[it * 256 + t];                       // coalesced: u*128+v
        __half2  h    = *(__half2*)&hw;
        float2   f    = __half22float2(h);                        // x=logsig(-l), y=l
        float    bitf = (float)((bits >> jsh) & 1u);
        acc1 = fmaf(swu * wv, f.x, acc1);
        acc2 = fmaf(bitf, f.y, acc2);
    }

    red[t] = acc1 + acc2;
    __syncthreads();
    for (int s = 128; s > 0; s >>= 1) {
        if (t < s) red[t] += red[t + s];
        __syncthreads();
    }
    if (t == 0) rec[b * Pn + p] = red[0];
}

// ---------------- K3: KL + RE = sum_b max_p rec ; out = mean(KL) - RE ----------------
__global__ void k_final(const float* __restrict__ mu,
                        const float* __restrict__ logstd,
                        const float* __restrict__ eps,
                        const float* __restrict__ ws,
                        float* __restrict__ out) {
    int t = threadIdx.x;   // 128 threads, one per b
    float kl = 0.f;
    for (int l = 0; l < Ln; ++l) {
        int   idx = t * Ln + l;
        float e = eps[idx], ls = logstd[idx];
        float z = mu[idx] + e * __expf(ls);
        kl += -0.5f * e * e - ls + 0.5f * z * z;   // 0.5*log(2pi) cancels
    }
    float m = -INFINITY;
    for (int p = 0; p < Pn; p++) m = fmaxf(m, ws[ROFF + t * Pn + p]);
    float contrib = kl * (1.0f / Bn) - m;
    __shared__ float red[128];
    red[t] = contrib;
    __syncthreads();
    for (int s = 64; s > 0; s >>= 1) {
        if (t < s) red[t] += red[t + s];
        __syncthreads();
    }
    if (t == 0) out[0] = red[0];
}

extern "C" void kernel_launch(void* const* d_in, const int* in_sizes, int n_in,
                              void* d_out, int out_size, void* d_ws, size_t ws_size,
                              hipStream_t stream) {
    const float* mu     = (const float*)d_in[0];
    const float* logstd = (const float*)d_in[1];
    const float* eps    = (const float*)d_in[2];
    const float* W      = (const float*)d_in[3];
    const int*   Adj    = (const int*)d_in[4];
    const int*   nm     = (const int*)d_in[5];
    const int*   perms  = (const int*)d_in[6];
    float* ws  = (float*)d_ws;
    float* out = (float*)d_out;

    hipLaunchKernelGGL(k_prep,  dim3(192 + Pn), dim3(256), 0, stream,
                       mu, logstd, eps, W, Adj, nm, ws);
    hipLaunchKernelGGL(k_main,  dim3(Pn * Bn),  dim3(256), 0, stream,
                       perms, ws, ws + ROFF);
    hipLaunchKernelGGL(k_final, dim3(1),        dim3(128), 0, stream,
                       mu, logstd, eps, ws, out);
}